// Round 1
// baseline (147.120 us; speedup 1.0000x reference)
//
#include <hip/hip_runtime.h>

#define NROWS 100000
#define IN_DIM 512
#define LDV 68   // padded leading dim for val LDS tile

typedef __attribute__((ext_vector_type(8))) short short8;
typedef __attribute__((ext_vector_type(4))) float f32x4;

__device__ inline unsigned short f2bf(float f) {
    union { float f; unsigned u; } v; v.f = f;
    unsigned u = v.u;
    return (unsigned short)((u + 0x7FFFu + ((u >> 16) & 1u)) >> 16);
}

// Prepack: build B-fragments (bf16) in exact MFMA lane order + fused que bias.
// B = [80 cols x 512 k]: cols 0..63 = Wv, 64..71 = Wq@Wk, 72..79 = 0.
// Bp layout: [t(5)][ks(16)][lane(64)][e(8)] bf16; col = t*16+(lane&15),
// k = ks*32 + (lane>>4)*8 + e.
__global__ void qg_prepack(const float* __restrict__ Wk, const float* __restrict__ bk,
                           const float* __restrict__ Wq, const float* __restrict__ bq,
                           const float* __restrict__ Wv,
                           unsigned short* __restrict__ Bp, float* __restrict__ qb) {
    int id = blockIdx.x * 256 + threadIdx.x;  // 0..5119
    if (id < 8) {
        float s = bq[id];
        #pragma unroll 4
        for (int j = 0; j < 100; ++j) s += Wq[id * 100 + j] * bk[j];
        qb[id] = s;
    }
    if (id >= 5120) return;
    int lane = id & 63;
    int ks = (id >> 6) & 15;
    int t = id >> 10;
    int c = t * 16 + (lane & 15);
    int kk = ks * 32 + (lane >> 4) * 8;
    unsigned short vals[8];
    #pragma unroll
    for (int e = 0; e < 8; ++e) {
        int k2 = kk + e;
        float w;
        if (c < 64) {
            w = Wv[c * IN_DIM + k2];
        } else if (c < 72) {
            float s = 0.f;
            #pragma unroll 4
            for (int j = 0; j < 100; ++j) s += Wq[(c - 64) * 100 + j] * Wk[j * IN_DIM + k2];
            w = s;
        } else {
            w = 0.f;
        }
        vals[e] = f2bf(w);
    }
    short8 pk;
    #pragma unroll
    for (int e = 0; e < 8; ++e) pk[e] = (short)vals[e];
    ((short8*)Bp)[id] = pk;
}

// Main: 4 waves/block, 16 rows/wave, 64 rows/block.
__global__ __launch_bounds__(256, 4) void qg_main(const float* __restrict__ x,
                                                  const float* __restrict__ bv,
                                                  const unsigned short* __restrict__ Bp,
                                                  const float* __restrict__ qb,
                                                  float* __restrict__ out) {
    __shared__ float vlds[4][16][LDV];
    __shared__ float wlds[4][16][8];
    const int tid = threadIdx.x;
    const int wid = tid >> 6;
    const int lane = tid & 63;
    const int g = lane >> 4;       // lane group (k sub-block)
    const int cl = lane & 15;      // col / row-within-tile index
    const int base_row = blockIdx.x * 64 + wid * 16;

    int arow = base_row + cl;
    if (arow > NROWS - 1) arow = NROWS - 1;   // clamp; OOB rows never stored
    const float* ap = x + (size_t)arow * IN_DIM + g * 8;
    const short8* bp8 = (const short8*)Bp;

    f32x4 acc[5];
    #pragma unroll
    for (int t = 0; t < 5; ++t) acc[t] = (f32x4){0.f, 0.f, 0.f, 0.f};

    #pragma unroll
    for (int ks = 0; ks < 16; ++ks) {
        float4 a0 = *(const float4*)(ap + ks * 32);
        float4 a1 = *(const float4*)(ap + ks * 32 + 4);
        short8 af;
        af[0] = (short)f2bf(a0.x); af[1] = (short)f2bf(a0.y);
        af[2] = (short)f2bf(a0.z); af[3] = (short)f2bf(a0.w);
        af[4] = (short)f2bf(a1.x); af[5] = (short)f2bf(a1.y);
        af[6] = (short)f2bf(a1.z); af[7] = (short)f2bf(a1.w);
        #pragma unroll
        for (int t = 0; t < 5; ++t) {
            short8 bf = bp8[(t * 16 + ks) * 64 + lane];
            acc[t] = __builtin_amdgcn_mfma_f32_16x16x32_bf16(af, bf, acc[t], 0, 0, 0);
        }
    }

    // Epilogue phase 1: C -> LDS (val + bias), que + bias.
    #pragma unroll
    for (int t = 0; t < 4; ++t) {
        float b = bv[t * 16 + cl];
        #pragma unroll
        for (int r = 0; r < 4; ++r)
            vlds[wid][g * 4 + r][t * 16 + cl] = acc[t][r] + b;
    }
    if (cl < 8) {
        float b = qb[cl];
        #pragma unroll
        for (int r = 0; r < 4; ++r)
            wlds[wid][g * 4 + r][cl] = acc[4][r] + b;
    }
    __syncthreads();

    // Phase 2: per-row softmax over 8 que values (lanes 0..15 each own a row).
    if (lane < 16) {
        float q[8];
        float m = -1e30f;
        #pragma unroll
        for (int k = 0; k < 8; ++k) { q[k] = wlds[wid][lane][k]; m = fmaxf(m, q[k]); }
        float s = 0.f;
        #pragma unroll
        for (int k = 0; k < 8; ++k) { q[k] = __expf(q[k] - m); s += q[k]; }
        float inv = 1.f / s;
        #pragma unroll
        for (int k = 0; k < 8; ++k) wlds[wid][lane][k] = q[k] * inv;
    }
    __syncthreads();

    // Phase 3: coalesced output: out[row][k][v] = w[k] * val[v].
    float4* outp = (float4*)out;
    #pragma unroll
    for (int it = 0; it < 32; ++it) {
        int row = it >> 1;
        int j = ((it & 1) << 6) + lane;   // float4 index within the 512-float row
        int grow = base_row + row;
        if (grow < NROWS) {
            int k = j >> 4;
            int v4 = j & 15;
            float w = wlds[wid][row][k];
            float4 vv = *(const float4*)&vlds[wid][row][v4 * 4];
            float4 o;
            o.x = w * vv.x; o.y = w * vv.y; o.z = w * vv.z; o.w = w * vv.w;
            outp[(size_t)grow * 128 + j] = o;
        }
    }
}

extern "C" void kernel_launch(void* const* d_in, const int* in_sizes, int n_in,
                              void* d_out, int out_size, void* d_ws, size_t ws_size,
                              hipStream_t stream) {
    const float* x  = (const float*)d_in[0];
    const float* Wk = (const float*)d_in[1];
    const float* bk = (const float*)d_in[2];
    const float* Wq = (const float*)d_in[3];
    const float* bq = (const float*)d_in[4];
    const float* Wv = (const float*)d_in[5];
    const float* bv = (const float*)d_in[6];
    float* out = (float*)d_out;

    unsigned short* Bp = (unsigned short*)d_ws;          // 5*16*64*8 bf16 = 81920 B
    float* qb = (float*)((char*)d_ws + 81920);           // 8 floats

    qg_prepack<<<20, 256, 0, stream>>>(Wk, bk, Wq, bq, Wv, Bp, qb);
    qg_main<<<1563, 256, 0, stream>>>(x, bv, Bp, qb, out);
}

// Round 2
// 131.426 us; speedup vs baseline: 1.1194x; 1.1194x over previous
//
#include <hip/hip_runtime.h>

#define NROWS 100000
#define IN_DIM 512

typedef __attribute__((ext_vector_type(8))) short short8;
typedef __attribute__((ext_vector_type(4))) float f32x4;
typedef unsigned int u32;
typedef const __attribute__((address_space(1))) u32* gptr_t;
typedef __attribute__((address_space(3))) u32* lptr_t;

__device__ inline unsigned short f2bf(float f) {
    union { float f; unsigned u; } v; v.f = f;
    unsigned u = v.u;
    return (unsigned short)((u + 0x7FFFu + ((u >> 16) & 1u)) >> 16);
}

// Prepack: build B-fragments (bf16) in exact MFMA lane order + fused que bias.
// B = [80 cols x 512 k]: cols 0..63 = Wv, 64..71 = Wq@Wk, 72..79 = 0.
// Bp layout: [t(5)][ks(16)][lane(64)][e(8)] bf16; col = t*16+(lane&15),
// k = ks*32 + (lane>>4)*8 + e.
__global__ void qg_prepack(const float* __restrict__ Wk, const float* __restrict__ bk,
                           const float* __restrict__ Wq, const float* __restrict__ bq,
                           const float* __restrict__ Wv,
                           unsigned short* __restrict__ Bp, float* __restrict__ qb) {
    int id = blockIdx.x * 256 + threadIdx.x;  // 0..5119
    if (id < 8) {
        float s = bq[id];
        #pragma unroll 4
        for (int j = 0; j < 100; ++j) s += Wq[id * 100 + j] * bk[j];
        qb[id] = s;
    }
    if (id >= 5120) return;
    int lane = id & 63;
    int ks = (id >> 6) & 15;
    int t = id >> 10;
    int c = t * 16 + (lane & 15);
    int kk = ks * 32 + (lane >> 4) * 8;
    short8 pk;
    #pragma unroll
    for (int e = 0; e < 8; ++e) {
        int k2 = kk + e;
        float w;
        if (c < 64) {
            w = Wv[c * IN_DIM + k2];
        } else if (c < 72) {
            float s = 0.f;
            #pragma unroll 4
            for (int j = 0; j < 100; ++j) s += Wq[(c - 64) * 100 + j] * Wk[j * IN_DIM + k2];
            w = s;
        } else {
            w = 0.f;
        }
        pk[e] = (short)f2bf(w);
    }
    ((short8*)Bp)[id] = pk;
}

// Main: 4 waves/block, 64 rows/block, BK=32 double-buffered LDS staging.
__global__ __launch_bounds__(256, 4) void qg_main(const float* __restrict__ x,
                                                  const float* __restrict__ bv,
                                                  const unsigned short* __restrict__ Bp,
                                                  const float* __restrict__ qb,
                                                  float* __restrict__ out) {
    __shared__ union {
        float xt[2][2048];                       // 2 x 8 KB staging (64 rows x 32 floats)
        struct { float v[64][68]; float w[64][8]; } ep;  // 19456 B epilogue
    } u;
    const int tid = threadIdx.x;
    const int wid = tid >> 6;
    const int lane = tid & 63;
    const int g = lane >> 4;       // k sub-block (k = g*8+e within a 32-K MFMA step)
    const int cl = lane & 15;      // row-within-wave / col-within-tile
    const int blockBase = blockIdx.x * 64;
    const short8* bp8 = (const short8*)Bp;

    // Per-thread staging descriptors: 2 chunks of 16 B each per step.
    // LDS linear offset o in [0,512): row = o>>3, swizzled slot = o&7,
    // global float4-slot k4 = (o&7) ^ (row&7).
    int srow[2], sk4[2], soff[2];
    #pragma unroll
    for (int c = 0; c < 2; ++c) {
        int o = c * 256 + tid;
        int row = o >> 3;
        int sl = o & 7;
        srow[c] = min(blockBase + row, NROWS - 1);
        sk4[c] = sl ^ (row & 7);
        soff[c] = o * 4;           // float offset within buffer
    }

    f32x4 acc[5];
    #pragma unroll
    for (int t = 0; t < 5; ++t) acc[t] = (f32x4){0.f, 0.f, 0.f, 0.f};

    short8 Breg[2][5];

    // Prologue: B(0) then STAGE(buf0, step0)
    #pragma unroll
    for (int t = 0; t < 5; ++t) Breg[0][t] = bp8[(t * 16 + 0) * 64 + lane];
    #pragma unroll
    for (int c = 0; c < 2; ++c) {
        const float* src = x + (size_t)srow[c] * IN_DIM + 0 * 32 + sk4[c] * 4;
        __builtin_amdgcn_global_load_lds((gptr_t)(const void*)src,
                                         (lptr_t)(void*)&u.xt[0][soff[c]], 16, 0, 0);
    }

    const int myrow = wid * 16 + cl;          // LDS row this lane's A-fragment uses
    const int sw0 = (g * 2) ^ (cl & 7);       // swizzled float4 slots
    const int sw1 = (g * 2 + 1) ^ (cl & 7);

    #pragma unroll
    for (int s = 0; s < 16; ++s) {
        const int cb = s & 1, nb = cb ^ 1;
        if (s < 15) {
            // B prefetch for s+1 (issued BEFORE stage so vmcnt FIFO keeps x-prefetch alive)
            #pragma unroll
            for (int t = 0; t < 5; ++t) Breg[nb][t] = bp8[(t * 16 + (s + 1)) * 64 + lane];
            // STAGE x for s+1 into buffer nb
            #pragma unroll
            for (int c = 0; c < 2; ++c) {
                const float* src = x + (size_t)srow[c] * IN_DIM + (s + 1) * 32 + sk4[c] * 4;
                __builtin_amdgcn_global_load_lds((gptr_t)(const void*)src,
                                                 (lptr_t)(void*)&u.xt[nb][soff[c]], 16, 0, 0);
            }
            asm volatile("s_waitcnt vmcnt(2)" ::: "memory");  // cur stage + B(s+1) done
        } else {
            asm volatile("s_waitcnt vmcnt(0)" ::: "memory");
        }
        __builtin_amdgcn_s_barrier();

        // A fragment from LDS (conflict-free via swizzle), cvt to bf16, 5 MFMAs
        const float4* xt4 = (const float4*)&u.xt[cb][0];
        float4 f0 = xt4[myrow * 8 + sw0];
        float4 f1 = xt4[myrow * 8 + sw1];
        short8 af;
        af[0] = (short)f2bf(f0.x); af[1] = (short)f2bf(f0.y);
        af[2] = (short)f2bf(f0.z); af[3] = (short)f2bf(f0.w);
        af[4] = (short)f2bf(f1.x); af[5] = (short)f2bf(f1.y);
        af[6] = (short)f2bf(f1.z); af[7] = (short)f2bf(f1.w);
        #pragma unroll
        for (int t = 0; t < 5; ++t)
            acc[t] = __builtin_amdgcn_mfma_f32_16x16x32_bf16(af, Breg[cb][t], acc[t], 0, 0, 0);

        asm volatile("s_waitcnt lgkmcnt(0)" ::: "memory");  // ds_reads done before overwrite
        __builtin_amdgcn_s_barrier();
    }

    // Epilogue phase 1: C -> LDS (val + bias), que + bias.
    #pragma unroll
    for (int t = 0; t < 4; ++t) {
        float b = bv[t * 16 + cl];
        #pragma unroll
        for (int r = 0; r < 4; ++r)
            u.ep.v[wid * 16 + g * 4 + r][t * 16 + cl] = acc[t][r] + b;
    }
    if (cl < 8) {
        float b = qb[cl];
        #pragma unroll
        for (int r = 0; r < 4; ++r)
            u.ep.w[wid * 16 + g * 4 + r][cl] = acc[4][r] + b;
    }
    __syncthreads();

    // Phase 2: per-row softmax over the 8 que values (threads 0..63, one row each).
    if (tid < 64) {
        float q[8];
        float m = -1e30f;
        #pragma unroll
        for (int k = 0; k < 8; ++k) { q[k] = u.ep.w[tid][k]; m = fmaxf(m, q[k]); }
        float ssum = 0.f;
        #pragma unroll
        for (int k = 0; k < 8; ++k) { q[k] = __expf(q[k] - m); ssum += q[k]; }
        float inv = 1.f / ssum;
        #pragma unroll
        for (int k = 0; k < 8; ++k) u.ep.w[tid][k] = q[k] * inv;
    }
    __syncthreads();

    // Phase 3: coalesced output: out[row][k][v] = w[k] * val[v].
    float4* outp = (float4*)out;
    #pragma unroll 8
    for (int it = 0; it < 32; ++it) {
        int idx = it * 256 + tid;
        int row = idx >> 7;             // 0..63
        int j = idx & 127;              // float4 index within 512-float out row
        int grow = blockBase + row;
        if (grow < NROWS) {
            float w = u.ep.w[row][j >> 4];
            float4 vv = *(const float4*)&u.ep.v[row][(j & 15) * 4];
            float4 o;
            o.x = w * vv.x; o.y = w * vv.y; o.z = w * vv.z; o.w = w * vv.w;
            outp[(size_t)grow * 128 + j] = o;
        }
    }
}

extern "C" void kernel_launch(void* const* d_in, const int* in_sizes, int n_in,
                              void* d_out, int out_size, void* d_ws, size_t ws_size,
                              hipStream_t stream) {
    const float* x  = (const float*)d_in[0];
    const float* Wk = (const float*)d_in[1];
    const float* bk = (const float*)d_in[2];
    const float* Wq = (const float*)d_in[3];
    const float* bq = (const float*)d_in[4];
    const float* Wv = (const float*)d_in[5];
    const float* bv = (const float*)d_in[6];
    float* out = (float*)d_out;

    unsigned short* Bp = (unsigned short*)d_ws;          // 5*16*64*8 bf16 = 81920 B
    float* qb = (float*)((char*)d_ws + 81920);           // 8 floats

    qg_prepack<<<20, 256, 0, stream>>>(Wk, bk, Wq, bq, Wv, Bp, qb);
    qg_main<<<1563, 256, 0, stream>>>(x, bv, Bp, qb, out);
}